// Round 8
// baseline (198.037 us; speedup 1.0000x reference)
//
#include <hip/hip_runtime.h>

#define N 1681
#define BS 32
#define BAND 41
#define NBLK (BS * BAND)          // 1312 pass1 blocks, one 41-row band each
#define THREADS 256
#define NROWS_TOTAL (BS * N)      // 53792
#define TOTELEM (BS * N * N)      // 90424352 elements per input array
#define PARTS_PER_MAT BAND        // 41 band-partials per matrix

// ws layout: bsums[128] f64 | dpart[NBLK*N] f32 | sp[53792] f32 | st[53792] f32

// dword-aligned float4: HW supports dword-aligned global_load_dwordx4
typedef __attribute__((ext_vector_type(4), aligned(4))) float f32x4u;

__global__ __launch_bounds__(THREADS, 4) void pass1_kernel(
    const float* __restrict__ pred,
    const float* __restrict__ targ,
    float* __restrict__ sp,
    float* __restrict__ st,
    float* __restrict__ dpart) {
  __shared__ float wp[BAND][4][2];   // per-row, per-wave {psq, tsq} partials

  const int b    = blockIdx.x;       // 0..1311, band b of matrix b/41
  const int tid  = threadIdx.x;
  const int lane = tid & 63;
  const int wid  = tid >> 6;
  const int Rbase = b * BAND;        // first global row of this band

  // static column ownership: slot0 = cols 4t..4t+3, slot1 = cols 1024+4t..
  const int e0 = 4 * tid;            // 0..1020, always in-row
  const int e1 = 1024 + 4 * tid;     // masked where >= N

  float dp0[4] = {0.f, 0.f, 0.f, 0.f};
  float dp1[4] = {0.f, 0.f, 0.f, 0.f};

  f32x4u pA0, pA1, tA0, tA1, pB0, pB1, tB0, tB1;
  f32x4u pC0, pC1, tC0, tC1, pD0, pD1, tD0, tD1;

#define ISSUE(P0, P1, T0, T1, ROWIDX) do {                               \
    const int s_  = (Rbase + (ROWIDX)) * N;                              \
    const int i1_ = min(s_ + e1, TOTELEM - 4);                           \
    P0 = *(const f32x4u*)(pred + s_ + e0);                               \
    T0 = *(const f32x4u*)(targ + s_ + e0);                               \
    P1 = *(const f32x4u*)(pred + i1_);                                   \
    T1 = *(const f32x4u*)(targ + i1_);                                   \
  } while (0)

#define COMPUTE(P0, P1, T0, T1, ROWIDX) do {                             \
    float psq = 0.0f, tsq = 0.0f;                                        \
    _Pragma("unroll")                                                    \
    for (int ee = 0; ee < 4; ++ee) {                                     \
      const float pv = P0[ee];                                           \
      const float tv = T0[ee];                                           \
      psq = fmaf(pv, pv, psq);                                           \
      tsq = fmaf(tv, tv, tsq);                                           \
      dp0[ee] = fmaf(pv, tv, dp0[ee]);                                   \
    }                                                                    \
    _Pragma("unroll")                                                    \
    for (int ee = 0; ee < 4; ++ee) {                                     \
      const bool ok = (e1 + ee) < N;                                     \
      const float pv = ok ? P1[ee] : 0.0f;                               \
      const float tv = ok ? T1[ee] : 0.0f;                               \
      psq = fmaf(pv, pv, psq);                                           \
      tsq = fmaf(tv, tv, tsq);                                           \
      dp1[ee] = fmaf(pv, tv, dp1[ee]);                                   \
    }                                                                    \
    _Pragma("unroll")                                                    \
    for (int off = 32; off > 0; off >>= 1) {                             \
      psq += __shfl_down(psq, off, 64);                                  \
      tsq += __shfl_down(tsq, off, 64);                                  \
    }                                                                    \
    if (lane == 0) { wp[ROWIDX][wid][0] = psq; wp[ROWIDX][wid][1] = tsq; } \
  } while (0)

  // 4-deep A/B/C/D ping-pong over the 41 rows; no in-loop barriers.
  // Steady state: 3 row-stages (24 dwordx4) in flight while computing one.
  ISSUE(pA0, pA1, tA0, tA1, 0);
  ISSUE(pB0, pB1, tB0, tB1, 1);
  ISSUE(pC0, pC1, tC0, tC1, 2);
  for (int r = 0; r < 36; r += 4) {
    ISSUE(pD0, pD1, tD0, tD1, r + 3);  COMPUTE(pA0, pA1, tA0, tA1, r);
    ISSUE(pA0, pA1, tA0, tA1, r + 4);  COMPUTE(pB0, pB1, tB0, tB1, r + 1);
    ISSUE(pB0, pB1, tB0, tB1, r + 5);  COMPUTE(pC0, pC1, tC0, tC1, r + 2);
    ISSUE(pC0, pC1, tC0, tC1, r + 6);  COMPUTE(pD0, pD1, tD0, tD1, r + 3);
  }
  // tail: A=36, B=37, C=38 loaded; rows 39,40 outstanding
  ISSUE(pD0, pD1, tD0, tD1, 39);  COMPUTE(pA0, pA1, tA0, tA1, 36);
  ISSUE(pA0, pA1, tA0, tA1, 40);  COMPUTE(pB0, pB1, tB0, tB1, 37);
  COMPUTE(pC0, pC1, tC0, tC1, 38);
  COMPUTE(pD0, pD1, tD0, tD1, 39);
  COMPUTE(pA0, pA1, tA0, tA1, 40);

  // column-dot partials: each column owned by exactly one thread -> plain stores
  {
    float* dst = dpart + (size_t)b * N;
    *(f32x4u*)(dst + e0) = *(f32x4u*)dp0;     // cols 4t..4t+3 (always < 1024)
#pragma unroll
    for (int ee = 0; ee < 4; ++ee)
      if (e1 + ee < N) dst[e1 + ee] = dp1[ee];
  }

  __syncthreads();
  if (tid < BAND) {
    sp[Rbase + tid] = wp[tid][0][0] + wp[tid][1][0] + wp[tid][2][0] + wp[tid][3][0];
  } else if (tid >= 64 && tid < 64 + BAND) {
    const int r = tid - 64;
    st[Rbase + r] = wp[r][0][1] + wp[r][1][1] + wp[r][2][1] + wp[r][3][1];
  }
}

__global__ __launch_bounds__(THREADS) void fin1_kernel(
    const float* __restrict__ sp,
    const float* __restrict__ st,
    const float* __restrict__ dpart,
    double* __restrict__ bsums) {
  __shared__ double red[4];

  double acc = 0.0;
  for (int g = blockIdx.x * THREADS + threadIdx.x; g < NROWS_TOTAL;
       g += gridDim.x * THREADS) {
    const int l = g / N;
    const int j = g - l * N;
    const float* __restrict__ dp = dpart + (size_t)l * PARTS_PER_MAT * N + j;
    float dv = 0.0f;
#pragma unroll 41
    for (int p = 0; p < PARTS_PER_MAT; ++p) dv += dp[(size_t)p * N];
    const double s = (double)sp[g] * (double)st[g];
    acc += (double)dv / sqrt(s);
  }
#pragma unroll
  for (int off = 32; off > 0; off >>= 1) acc += __shfl_down(acc, off, 64);
  const int wid = threadIdx.x >> 6;
  if ((threadIdx.x & 63) == 0) red[wid] = acc;
  __syncthreads();
  if (threadIdx.x == 0)
    bsums[blockIdx.x] = red[0] + red[1] + red[2] + red[3];
}

__global__ __launch_bounds__(64) void fin2_kernel(
    const double* __restrict__ bsums, float* __restrict__ out) {
  double acc = bsums[threadIdx.x] + bsums[threadIdx.x + 64];
#pragma unroll
  for (int off = 32; off > 0; off >>= 1) acc += __shfl_down(acc, off, 64);
  if (threadIdx.x == 0)
    out[0] = (float)(-acc / ((double)BS * (double)N));
}

extern "C" void kernel_launch(void* const* d_in, const int* in_sizes, int n_in,
                              void* d_out, int out_size, void* d_ws, size_t ws_size,
                              hipStream_t stream) {
  const float* pred = (const float*)d_in[0];
  const float* targ = (const float*)d_in[1];

  double* bsums = (double*)d_ws;                          // 128 doubles
  float*  dpart = (float*)(bsums + 128);                  // NBLK*N floats (~8.8 MB)
  float*  sp    = dpart + (size_t)NBLK * N;               // 53792 floats
  float*  st    = sp + (size_t)NROWS_TOTAL;               // 53792 floats

  pass1_kernel<<<NBLK, THREADS, 0, stream>>>(pred, targ, sp, st, dpart);
  fin1_kernel<<<128, THREADS, 0, stream>>>(sp, st, dpart, bsums);
  fin2_kernel<<<1, 64, 0, stream>>>(bsums, (float*)d_out);
}

// Round 9
// 149.620 us; speedup vs baseline: 1.3236x; 1.3236x over previous
//
#include <hip/hip_runtime.h>

#define N 1681
#define BS 32
#define BAND 41
#define NBLK (BS * BAND)          // 1312 pass1 blocks, one 41-row band each
#define THREADS 256
#define NROWS_TOTAL (BS * N)      // 53792
#define TOTELEM (BS * N * N)      // 90424352 elements per input array
#define PARTS_PER_MAT BAND        // 41 band-partials per matrix

// ws layout: bsums[128] f64 | dpart[NBLK*N] f32 | sp[53792] f32 | st[53792] f32

// dword-aligned float4: HW supports dword-aligned global_load_dwordx4
typedef __attribute__((ext_vector_type(4), aligned(4))) float f32x4u;

__global__ __launch_bounds__(THREADS, 4) void pass1_kernel(
    const float* __restrict__ pred,
    const float* __restrict__ targ,
    float* __restrict__ sp,
    float* __restrict__ st,
    float* __restrict__ dpart) {
  __shared__ float wp[BAND][4][2];   // per-row, per-wave {psq, tsq} partials

  const int b    = blockIdx.x;       // 0..1311, band b of matrix b/41
  const int tid  = threadIdx.x;
  const int lane = tid & 63;
  const int wid  = tid >> 6;
  const int Rbase = b * BAND;        // first global row of this band

  // static column ownership: slot0 = cols 4t..4t+3, slot1 = cols 1024+4t..
  const int e0 = 4 * tid;            // 0..1020, always in-row
  const int e1 = 1024 + 4 * tid;     // masked where >= N

  float dp0[4] = {0.f, 0.f, 0.f, 0.f};
  float dp1[4] = {0.f, 0.f, 0.f, 0.f};

  f32x4u pA0, pA1, tA0, tA1, pB0, pB1, tB0, tB1, pC0, pC1, tC0, tC1;

#define ISSUE(P0, P1, T0, T1, ROWIDX) do {                               \
    const int s_  = (Rbase + (ROWIDX)) * N;                              \
    const int i1_ = min(s_ + e1, TOTELEM - 4);                           \
    P0 = *(const f32x4u*)(pred + s_ + e0);                               \
    T0 = *(const f32x4u*)(targ + s_ + e0);                               \
    P1 = *(const f32x4u*)(pred + i1_);                                   \
    T1 = *(const f32x4u*)(targ + i1_);                                   \
  } while (0)

#define COMPUTE(P0, P1, T0, T1, ROWIDX) do {                             \
    float psq = 0.0f, tsq = 0.0f;                                        \
    _Pragma("unroll")                                                    \
    for (int ee = 0; ee < 4; ++ee) {                                     \
      const float pv = P0[ee];                                           \
      const float tv = T0[ee];                                           \
      psq = fmaf(pv, pv, psq);                                           \
      tsq = fmaf(tv, tv, tsq);                                           \
      dp0[ee] = fmaf(pv, tv, dp0[ee]);                                   \
    }                                                                    \
    _Pragma("unroll")                                                    \
    for (int ee = 0; ee < 4; ++ee) {                                     \
      const bool ok = (e1 + ee) < N;                                     \
      const float pv = ok ? P1[ee] : 0.0f;                               \
      const float tv = ok ? T1[ee] : 0.0f;                               \
      psq = fmaf(pv, pv, psq);                                           \
      tsq = fmaf(tv, tv, tsq);                                           \
      dp1[ee] = fmaf(pv, tv, dp1[ee]);                                   \
    }                                                                    \
    _Pragma("unroll")                                                    \
    for (int off = 32; off > 0; off >>= 1) {                             \
      psq += __shfl_down(psq, off, 64);                                  \
      tsq += __shfl_down(tsq, off, 64);                                  \
    }                                                                    \
    if (lane == 0) { wp[ROWIDX][wid][0] = psq; wp[ROWIDX][wid][1] = tsq; } \
  } while (0)

  // 3-deep A/B/C rotation over the 41 rows; no in-loop barriers.
  // Steady state: 2 row-stages (8 dwordx4/thread-group) in flight per wave.
  ISSUE(pA0, pA1, tA0, tA1, 0);
  ISSUE(pB0, pB1, tB0, tB1, 1);
  for (int r = 0; r <= 36; r += 3) {
    ISSUE(pC0, pC1, tC0, tC1, r + 2);  COMPUTE(pA0, pA1, tA0, tA1, r);
    ISSUE(pA0, pA1, tA0, tA1, r + 3);  COMPUTE(pB0, pB1, tB0, tB1, r + 1);
    ISSUE(pB0, pB1, tB0, tB1, r + 4);  COMPUTE(pC0, pC1, tC0, tC1, r + 2);
  }
  // after r=36 iteration: rows 0..38 computed, rows 39 (A), 40 (B) loaded
  COMPUTE(pA0, pA1, tA0, tA1, 39);
  COMPUTE(pB0, pB1, tB0, tB1, 40);

  // column-dot partials: each column owned by exactly one thread -> plain stores
  {
    float* dst = dpart + (size_t)b * N;
    *(f32x4u*)(dst + e0) = *(f32x4u*)dp0;     // cols 4t..4t+3 (always < 1024)
#pragma unroll
    for (int ee = 0; ee < 4; ++ee)
      if (e1 + ee < N) dst[e1 + ee] = dp1[ee];
  }

  __syncthreads();
  if (tid < BAND) {
    sp[Rbase + tid] = wp[tid][0][0] + wp[tid][1][0] + wp[tid][2][0] + wp[tid][3][0];
  } else if (tid >= 64 && tid < 64 + BAND) {
    const int r = tid - 64;
    st[Rbase + r] = wp[r][0][1] + wp[r][1][1] + wp[r][2][1] + wp[r][3][1];
  }
}

__global__ __launch_bounds__(THREADS) void fin1_kernel(
    const float* __restrict__ sp,
    const float* __restrict__ st,
    const float* __restrict__ dpart,
    double* __restrict__ bsums) {
  __shared__ double red[4];

  double acc = 0.0;
  for (int g = blockIdx.x * THREADS + threadIdx.x; g < NROWS_TOTAL;
       g += gridDim.x * THREADS) {
    const int l = g / N;
    const int j = g - l * N;
    const float* __restrict__ dp = dpart + (size_t)l * PARTS_PER_MAT * N + j;
    float dv = 0.0f;
#pragma unroll 41
    for (int p = 0; p < PARTS_PER_MAT; ++p) dv += dp[(size_t)p * N];
    const double s = (double)sp[g] * (double)st[g];
    acc += (double)dv / sqrt(s);
  }
#pragma unroll
  for (int off = 32; off > 0; off >>= 1) acc += __shfl_down(acc, off, 64);
  const int wid = threadIdx.x >> 6;
  if ((threadIdx.x & 63) == 0) red[wid] = acc;
  __syncthreads();
  if (threadIdx.x == 0)
    bsums[blockIdx.x] = red[0] + red[1] + red[2] + red[3];
}

__global__ __launch_bounds__(64) void fin2_kernel(
    const double* __restrict__ bsums, float* __restrict__ out) {
  double acc = bsums[threadIdx.x] + bsums[threadIdx.x + 64];
#pragma unroll
  for (int off = 32; off > 0; off >>= 1) acc += __shfl_down(acc, off, 64);
  if (threadIdx.x == 0)
    out[0] = (float)(-acc / ((double)BS * (double)N));
}

extern "C" void kernel_launch(void* const* d_in, const int* in_sizes, int n_in,
                              void* d_out, int out_size, void* d_ws, size_t ws_size,
                              hipStream_t stream) {
  const float* pred = (const float*)d_in[0];
  const float* targ = (const float*)d_in[1];

  double* bsums = (double*)d_ws;                          // 128 doubles
  float*  dpart = (float*)(bsums + 128);                  // NBLK*N floats (~8.8 MB)
  float*  sp    = dpart + (size_t)NBLK * N;               // 53792 floats
  float*  st    = sp + (size_t)NROWS_TOTAL;               // 53792 floats

  pass1_kernel<<<NBLK, THREADS, 0, stream>>>(pred, targ, sp, st, dpart);
  fin1_kernel<<<128, THREADS, 0, stream>>>(sp, st, dpart, bsums);
  fin2_kernel<<<1, 64, 0, stream>>>(bsums, (float*)d_out);
}